// Round 1
// baseline (187.237 us; speedup 1.0000x reference)
//
#include <hip/hip_runtime.h>
#include <stdint.h>

typedef unsigned long long u64;

// Problem constants (from reference file)
constexpr int B_ = 4;
constexpr int N_ = 160;
constexpr int T_ = 512;
constexpr int W_ = T_ / 64;   // 8 u64 words per 512-bit row

// ---------------------------------------------------------------------------
// Kernel 1: gather + bit-pack tag rows. grid = B*N blocks, 64 threads.
// tags[row][w] bit l  <=>  api_tag_embedding[pred[row]][w*64+l] != 0
// ---------------------------------------------------------------------------
__global__ __launch_bounds__(64) void pack_tags(const float* __restrict__ emb,
                                                const int* __restrict__ preds,
                                                u64* __restrict__ tags) {
    int row  = blockIdx.x;            // b*N + r
    int lane = threadIdx.x;           // 0..63
    const float* src = emb + (long long)preds[row] * T_;
#pragma unroll
    for (int w = 0; w < W_; ++w) {
        float v = src[w * 64 + lane];
        u64 m = __ballot(v != 0.0f);
        if (lane == 0) tags[(long long)row * W_ + w] = m;
    }
}

// ---------------------------------------------------------------------------
// Kernel 2: bit-pack M. grid = B blocks, 64 threads.
// ---------------------------------------------------------------------------
__global__ __launch_bounds__(64) void pack_M(const float* __restrict__ Mf,
                                             u64* __restrict__ Mp) {
    int b    = blockIdx.x;
    int lane = threadIdx.x;
#pragma unroll
    for (int w = 0; w < W_; ++w) {
        float v = Mf[(long long)b * T_ + w * 64 + lane];
        u64 m = __ballot(v != 0.0f);
        if (lane == 0) Mp[b * W_ + w] = m;
    }
}

// ---------------------------------------------------------------------------
// Kernel 3: per-batch prefix-OR P, cU[k] = popcnt(M & ~P[k]), Mc = popcnt(M)+1
// grid = B blocks, 64 threads (lanes 0..W_-1 own one word each).
// ---------------------------------------------------------------------------
__global__ __launch_bounds__(64) void prefix_stats(const u64* __restrict__ tags,
                                                   const u64* __restrict__ Mp,
                                                   u64* __restrict__ P,
                                                   float* __restrict__ cU,
                                                   float* __restrict__ Mc) {
    int b    = blockIdx.x;
    int lane = threadIdx.x;
    u64 Pw = 0;
    u64 Mw = (lane < W_) ? Mp[b * W_ + lane] : 0ull;
    for (int r = 0; r < N_; ++r) {
        if (lane < W_) Pw |= tags[((long long)b * N_ + r) * W_ + lane];
        int c = (lane < W_) ? __popcll(Mw & ~Pw) : 0;
        c += __shfl_down(c, 4, 64);
        c += __shfl_down(c, 2, 64);
        c += __shfl_down(c, 1, 64);
        if (lane < W_) P[((long long)b * N_ + r) * W_ + lane] = Pw;
        if (lane == 0) cU[b * N_ + r] = (float)c;
    }
    if (lane == 0) {
        int c = 0;
        for (int w = 0; w < W_; ++w) c += __popcll(Mp[b * W_ + w]);
        Mc[b] = (float)(c + 1);
    }
}

// ---------------------------------------------------------------------------
// Kernel 4: main. grid = (N, B), 192 threads. Block (i,b):
//   thread j holds b_j = M & ~tag[j]; sweep k = i..N-2 with incremental
//   aw = M & ~A[k,i]  (aw_{k+1} = aw_k & ~tag[k-1] for k>=i+2),
//   acc_j += (cU[k] - popcnt(aw & b_j)) / log2(k+2)   for j > k
//   partial(b,i) = sum_j sigmoid(s_j - s_i) * acc_j / Mc_b
// ---------------------------------------------------------------------------
__global__ __launch_bounds__(192) void lambda_main(const u64* __restrict__ tags,
                                                   const u64* __restrict__ Mp,
                                                   const u64* __restrict__ P,
                                                   const float* __restrict__ cU,
                                                   const float* __restrict__ Mc,
                                                   const float* __restrict__ scores,
                                                   double* __restrict__ partials) {
    __shared__ u64 tagsL[N_ * W_];
    __shared__ float cUL[N_];
    __shared__ float invlogL[N_];
    __shared__ float scoresL[N_];
    __shared__ float redF[3];

    const int i   = blockIdx.x;
    const int b   = blockIdx.y;
    const int tid = threadIdx.x;

    for (int x = tid; x < N_ * W_; x += blockDim.x)
        tagsL[x] = tags[(long long)b * N_ * W_ + x];
    for (int x = tid; x < N_; x += blockDim.x) {
        cUL[x]     = cU[b * N_ + x];
        scoresL[x] = scores[b * N_ + x];
        invlogL[x] = 1.0f / log2f((float)(x + 2));
    }
    __syncthreads();

    // uniform: M and initial aw = M & ~pre_i
    u64 Mw[W_], aw[W_];
#pragma unroll
    for (int w = 0; w < W_; ++w) Mw[w] = Mp[b * W_ + w];
    if (i == 1) {
#pragma unroll
        for (int w = 0; w < W_; ++w) aw[w] = Mw[w];     // pre = 0
    } else {
        int src = (i == 0) ? (N_ - 2) : (i - 2);
#pragma unroll
        for (int w = 0; w < W_; ++w)
            aw[w] = Mw[w] & ~P[((long long)b * N_ + src) * W_ + w];
    }

    const int j = tid;
    u64 Bw[W_];
    float lam = 0.0f;
    if (j < N_) {
#pragma unroll
        for (int w = 0; w < W_; ++w) Bw[w] = Mw[w] & ~tagsL[j * W_ + w];
        lam = 1.0f / (1.0f + __expf(scoresL[i] - scoresL[j]));
    }

    float acc = 0.0f;
    for (int k = i; k <= N_ - 2; ++k) {
        if (k >= i + 2) {
#pragma unroll
            for (int w = 0; w < W_; ++w) aw[w] &= ~tagsL[(k - 1) * W_ + w];
        }
        if (j > k && j < N_) {
            int c = 0;
#pragma unroll
            for (int w = 0; w < W_; ++w) c += __popcll(aw[w] & Bw[w]);
            acc += invlogL[k] * (cUL[k] - (float)c);
        }
    }

    float val = (j < N_) ? lam * acc : 0.0f;
    // block reduce (3 waves)
    for (int off = 32; off >= 1; off >>= 1) val += __shfl_down(val, off, 64);
    if ((tid & 63) == 0) redF[tid >> 6] = val;
    __syncthreads();
    if (tid == 0) {
        float s = redF[0] + redF[1] + redF[2];
        partials[b * N_ + i] = (double)s / (double)Mc[b];
    }
}

// ---------------------------------------------------------------------------
// Kernel 5: reduce partials -> scalar. 1 block, 256 threads.
// ---------------------------------------------------------------------------
__global__ __launch_bounds__(256) void finalize(const double* __restrict__ partials,
                                                float* __restrict__ out) {
    __shared__ double redD[4];
    const int tid = threadIdx.x;
    double s = 0.0;
    for (int x = tid; x < B_ * N_; x += 256) s += partials[x];
    for (int off = 32; off >= 1; off >>= 1) s += __shfl_down(s, off, 64);
    if ((tid & 63) == 0) redD[tid >> 6] = s;
    __syncthreads();
    if (tid == 0) {
        double t = redD[0] + redD[1] + redD[2] + redD[3];
        out[0] = (float)(t / ((double)(N_ + 1) * (double)B_));
    }
}

// ---------------------------------------------------------------------------
extern "C" void kernel_launch(void* const* d_in, const int* in_sizes, int n_in,
                              void* d_out, int out_size, void* d_ws, size_t ws_size,
                              hipStream_t stream) {
    const float* y_scores = (const float*)d_in[0];   // B*N f32
    const float* Mf       = (const float*)d_in[1];   // B*T f32
    const float* emb      = (const float*)d_in[2];   // NUM_API*T f32
    const int*   preds    = (const int*)d_in[3];     // B*N i32
    float* out = (float*)d_out;

    // workspace layout (all 8-byte aligned)
    u64* tags = (u64*)d_ws;                               // B*N*W
    u64* P    = tags + (size_t)B_ * N_ * W_;              // B*N*W
    u64* Mp   = P + (size_t)B_ * N_ * W_;                 // B*W
    double* partials = (double*)(Mp + B_ * W_);           // B*N
    float* cU = (float*)(partials + B_ * N_);             // B*N
    float* Mc = cU + B_ * N_;                             // B

    pack_tags<<<B_ * N_, 64, 0, stream>>>(emb, preds, tags);
    pack_M<<<B_, 64, 0, stream>>>(Mf, Mp);
    prefix_stats<<<B_, 64, 0, stream>>>(tags, Mp, P, cU, Mc);
    dim3 grid(N_, B_);
    lambda_main<<<grid, 192, 0, stream>>>(tags, Mp, P, cU, Mc, y_scores, partials);
    finalize<<<1, 256, 0, stream>>>(partials, out);
}

// Round 2
// 134.658 us; speedup vs baseline: 1.3905x; 1.3905x over previous
//
#include <hip/hip_runtime.h>
#include <stdint.h>

typedef unsigned long long u64;

// Problem constants (from reference file)
constexpr int B_ = 4;
constexpr int N_ = 160;
constexpr int T_ = 512;
constexpr int W_ = T_ / 64;   // 8 u64 words per 512-bit row

// ---------------------------------------------------------------------------
// Kernel 1: gather + bit-pack tag rows. grid = B*N blocks, 64 threads.
// ---------------------------------------------------------------------------
__global__ __launch_bounds__(64) void pack_tags(const float* __restrict__ emb,
                                                const int* __restrict__ preds,
                                                u64* __restrict__ tags) {
    int row  = blockIdx.x;            // b*N + r
    int lane = threadIdx.x;           // 0..63
    const float* src = emb + (long long)preds[row] * T_;
#pragma unroll
    for (int w = 0; w < W_; ++w) {
        float v = src[w * 64 + lane];
        u64 m = __ballot(v != 0.0f);
        if (lane == 0) tags[(long long)row * W_ + w] = m;
    }
}

// ---------------------------------------------------------------------------
// Kernel 2 (fused pack_M + parallel prefix-OR scan + stats).
// grid = B blocks, 256 threads.
//   Mp[b]   = bit-packed M
//   P[b][r] = OR of tags[b][0..r]  (inclusive scan, Hillis-Steele in LDS)
//   cU[b][r]= popcnt(M & ~P[r]),  Mc[b] = popcnt(M)+1
// ---------------------------------------------------------------------------
__global__ __launch_bounds__(256) void pack_scan(const float* __restrict__ Mf,
                                                 const u64* __restrict__ tags,
                                                 u64* __restrict__ Mp,
                                                 u64* __restrict__ P,
                                                 float* __restrict__ cU,
                                                 float* __restrict__ Mc) {
    __shared__ u64 S0[N_ * W_];
    __shared__ u64 S1[N_ * W_];
    __shared__ u64 Msh[W_];

    const int b    = blockIdx.x;
    const int tid  = threadIdx.x;
    const int lane = tid & 63;
    const int wv   = tid >> 6;        // wave id, 0..3

    // pack M: wave wv handles words wv, wv+4
    for (int w = wv; w < W_; w += 4) {
        float v = Mf[(long long)b * T_ + w * 64 + lane];
        u64 m = __ballot(v != 0.0f);
        if (lane == 0) { Msh[w] = m; Mp[b * W_ + w] = m; }
    }
    // load this batch's tags into LDS (coalesced u64)
    for (int x = tid; x < N_ * W_; x += 256)
        S0[x] = tags[(long long)b * N_ * W_ + x];
    __syncthreads();

    // Hillis-Steele inclusive OR-scan along r (layout x = r*W_ + w)
    u64* src = S0;
    u64* dst = S1;
    for (int d = 1; d < N_; d <<= 1) {
        for (int x = tid; x < N_ * W_; x += 256) {
            int r = x >> 3;           // W_ == 8
            u64 v = src[x];
            if (r >= d) v |= src[x - d * W_];
            dst[x] = v;
        }
        __syncthreads();
        u64* t = src; src = dst; dst = t;
    }

    // write P
    for (int x = tid; x < N_ * W_; x += 256)
        P[(long long)b * N_ * W_ + x] = src[x];

    // cU[r] = popcnt(M & ~P[r]); one thread per row
    if (tid < N_) {
        int c = 0;
#pragma unroll
        for (int w = 0; w < W_; ++w)
            c += __popcll(Msh[w] & ~src[tid * W_ + w]);
        cU[b * N_ + tid] = (float)c;
    }
    if (tid == 0) {
        int c = 0;
#pragma unroll
        for (int w = 0; w < W_; ++w) c += __popcll(Msh[w]);
        Mc[b] = (float)(c + 1);
    }
}

// ---------------------------------------------------------------------------
// Kernel 3: main. grid = (N, B), 192 threads. Block (i,b):
//   thread j holds b_j = M & ~tag[j]; sweep k = i..N-2 with incremental
//   aw = M & ~A[k,i], acc_j += (cU[k] - popcnt(aw & b_j)) / log2(k+2) for j>k
//   partial(b,i) = sum_j sigmoid(s_j - s_i) * acc_j / Mc_b
// ---------------------------------------------------------------------------
__global__ __launch_bounds__(192) void lambda_main(const u64* __restrict__ tags,
                                                   const u64* __restrict__ Mp,
                                                   const u64* __restrict__ P,
                                                   const float* __restrict__ cU,
                                                   const float* __restrict__ Mc,
                                                   const float* __restrict__ scores,
                                                   double* __restrict__ partials) {
    __shared__ u64 tagsL[N_ * W_];
    __shared__ float cUL[N_];
    __shared__ float invlogL[N_];
    __shared__ float scoresL[N_];
    __shared__ float redF[3];

    const int i   = blockIdx.x;
    const int b   = blockIdx.y;
    const int tid = threadIdx.x;

    for (int x = tid; x < N_ * W_; x += blockDim.x)
        tagsL[x] = tags[(long long)b * N_ * W_ + x];
    for (int x = tid; x < N_; x += blockDim.x) {
        cUL[x]     = cU[b * N_ + x];
        scoresL[x] = scores[b * N_ + x];
        invlogL[x] = 1.0f / log2f((float)(x + 2));
    }
    __syncthreads();

    // uniform: M and initial aw = M & ~pre_i
    u64 Mw[W_], aw[W_];
#pragma unroll
    for (int w = 0; w < W_; ++w) Mw[w] = Mp[b * W_ + w];
    if (i == 1) {
#pragma unroll
        for (int w = 0; w < W_; ++w) aw[w] = Mw[w];     // pre = 0
    } else {
        int src = (i == 0) ? (N_ - 2) : (i - 2);
#pragma unroll
        for (int w = 0; w < W_; ++w)
            aw[w] = Mw[w] & ~P[((long long)b * N_ + src) * W_ + w];
    }

    const int j = tid;
    u64 Bw[W_];
    float lam = 0.0f;
    if (j < N_) {
#pragma unroll
        for (int w = 0; w < W_; ++w) Bw[w] = Mw[w] & ~tagsL[j * W_ + w];
        lam = 1.0f / (1.0f + __expf(scoresL[i] - scoresL[j]));
    }

    float acc = 0.0f;
    for (int k = i; k <= N_ - 2; ++k) {
        if (k >= i + 2) {
#pragma unroll
            for (int w = 0; w < W_; ++w) aw[w] &= ~tagsL[(k - 1) * W_ + w];
        }
        if (j > k && j < N_) {
            int c = 0;
#pragma unroll
            for (int w = 0; w < W_; ++w) c += __popcll(aw[w] & Bw[w]);
            acc += invlogL[k] * (cUL[k] - (float)c);
        }
    }

    float val = (j < N_) ? lam * acc : 0.0f;
    for (int off = 32; off >= 1; off >>= 1) val += __shfl_down(val, off, 64);
    if ((tid & 63) == 0) redF[tid >> 6] = val;
    __syncthreads();
    if (tid == 0) {
        float s = redF[0] + redF[1] + redF[2];
        partials[b * N_ + i] = (double)s / (double)Mc[b];
    }
}

// ---------------------------------------------------------------------------
// Kernel 4: reduce partials -> scalar. 1 block, 256 threads.
// ---------------------------------------------------------------------------
__global__ __launch_bounds__(256) void finalize(const double* __restrict__ partials,
                                                float* __restrict__ out) {
    __shared__ double redD[4];
    const int tid = threadIdx.x;
    double s = 0.0;
    for (int x = tid; x < B_ * N_; x += 256) s += partials[x];
    for (int off = 32; off >= 1; off >>= 1) s += __shfl_down(s, off, 64);
    if ((tid & 63) == 0) redD[tid >> 6] = s;
    __syncthreads();
    if (tid == 0) {
        double t = redD[0] + redD[1] + redD[2] + redD[3];
        out[0] = (float)(t / ((double)(N_ + 1) * (double)B_));
    }
}

// ---------------------------------------------------------------------------
extern "C" void kernel_launch(void* const* d_in, const int* in_sizes, int n_in,
                              void* d_out, int out_size, void* d_ws, size_t ws_size,
                              hipStream_t stream) {
    const float* y_scores = (const float*)d_in[0];   // B*N f32
    const float* Mf       = (const float*)d_in[1];   // B*T f32
    const float* emb      = (const float*)d_in[2];   // NUM_API*T f32
    const int*   preds    = (const int*)d_in[3];     // B*N i32
    float* out = (float*)d_out;

    // workspace layout (all 8-byte aligned)
    u64* tags = (u64*)d_ws;                               // B*N*W
    u64* P    = tags + (size_t)B_ * N_ * W_;              // B*N*W
    u64* Mp   = P + (size_t)B_ * N_ * W_;                 // B*W
    double* partials = (double*)(Mp + B_ * W_);           // B*N
    float* cU = (float*)(partials + B_ * N_);             // B*N
    float* Mc = cU + B_ * N_;                             // B

    pack_tags<<<B_ * N_, 64, 0, stream>>>(emb, preds, tags);
    pack_scan<<<B_, 256, 0, stream>>>(Mf, tags, Mp, P, cU, Mc);
    dim3 grid(N_, B_);
    lambda_main<<<grid, 192, 0, stream>>>(tags, Mp, P, cU, Mc, y_scores, partials);
    finalize<<<1, 256, 0, stream>>>(partials, out);
}

// Round 3
// 113.095 us; speedup vs baseline: 1.6556x; 1.1907x over previous
//
#include <hip/hip_runtime.h>
#include <stdint.h>

typedef unsigned long long u64;

// Problem constants (from reference file)
constexpr int B_ = 4;
constexpr int N_ = 160;
constexpr int T_ = 512;
constexpr int W_ = T_ / 64;   // 8 u64 words per 512-bit row

// ---------------------------------------------------------------------------
// Kernel 1: gather + bit-pack tag rows. grid = B*N blocks, 64 threads.
// ---------------------------------------------------------------------------
__global__ __launch_bounds__(64) void pack_tags(const float* __restrict__ emb,
                                                const int* __restrict__ preds,
                                                u64* __restrict__ tags) {
    int row  = blockIdx.x;            // b*N + r
    int lane = threadIdx.x;           // 0..63
    const float* src = emb + (long long)preds[row] * T_;
#pragma unroll
    for (int w = 0; w < W_; ++w) {
        float v = src[w * 64 + lane];
        u64 m = __ballot(v != 0.0f);
        if (lane == 0) tags[(long long)row * W_ + w] = m;
    }
}

// ---------------------------------------------------------------------------
// Kernel 2 (fused pack_M + parallel prefix-OR scan + stats).
// grid = B blocks, 256 threads.
// ---------------------------------------------------------------------------
__global__ __launch_bounds__(256) void pack_scan(const float* __restrict__ Mf,
                                                 const u64* __restrict__ tags,
                                                 u64* __restrict__ Mp,
                                                 u64* __restrict__ P,
                                                 float* __restrict__ cU,
                                                 float* __restrict__ Mc) {
    __shared__ u64 S0[N_ * W_];
    __shared__ u64 S1[N_ * W_];
    __shared__ u64 Msh[W_];

    const int b    = blockIdx.x;
    const int tid  = threadIdx.x;
    const int lane = tid & 63;
    const int wv   = tid >> 6;        // wave id, 0..3

    for (int w = wv; w < W_; w += 4) {
        float v = Mf[(long long)b * T_ + w * 64 + lane];
        u64 m = __ballot(v != 0.0f);
        if (lane == 0) { Msh[w] = m; Mp[b * W_ + w] = m; }
    }
    for (int x = tid; x < N_ * W_; x += 256)
        S0[x] = tags[(long long)b * N_ * W_ + x];
    __syncthreads();

    u64* src = S0;
    u64* dst = S1;
    for (int d = 1; d < N_; d <<= 1) {
        for (int x = tid; x < N_ * W_; x += 256) {
            int r = x >> 3;           // W_ == 8
            u64 v = src[x];
            if (r >= d) v |= src[x - d * W_];
            dst[x] = v;
        }
        __syncthreads();
        u64* t = src; src = dst; dst = t;
    }

    for (int x = tid; x < N_ * W_; x += 256)
        P[(long long)b * N_ * W_ + x] = src[x];

    if (tid < N_) {
        int c = 0;
#pragma unroll
        for (int w = 0; w < W_; ++w)
            c += __popcll(Msh[w] & ~src[tid * W_ + w]);
        cU[b * N_ + tid] = (float)c;
    }
    if (tid == 0) {
        int c = 0;
#pragma unroll
        for (int w = 0; w < W_; ++w) c += __popcll(Msh[w]);
        Mc[b] = (float)(c + 1);
    }
}

// ---------------------------------------------------------------------------
// Kernel 3: main, restructured. grid = (N, B) over k, 256 threads.
// Block (k,b):
//   suffix-OR scan: suf[r] = OR tags[r..k-1]      (8-step parallel LDS scan)
//   awT[i] = M & ~pre_i & ~suf[i+1]  (i<=k-2; else M & ~pre_i)
//   bT[j]  = M & ~tags[j]
//   V = invlog[k] * sum_{i<=k, j>k} lam(i,j)*(cU[k]-popcnt(awT[i]&bT[j]))
// 256 threads stride the (k+1)*(N-1-k) pair space (balanced, no serial chain).
// All LDS arrays transposed [w][row], pad LD=161 -> consecutive lanes hit
// consecutive u64 (2-way bank aliasing = free on gfx950).
// ---------------------------------------------------------------------------
__global__ __launch_bounds__(256) void lambda_main(const u64* __restrict__ tags,
                                                   const u64* __restrict__ Mp,
                                                   const u64* __restrict__ P,
                                                   const float* __restrict__ cU,
                                                   const float* __restrict__ Mc,
                                                   const float* __restrict__ scores,
                                                   double* __restrict__ partials) {
    constexpr int LD = N_ + 1;        // 161, pad to break bank strides
    __shared__ u64 tagsT[W_ * LD];
    __shared__ u64 bufA[W_ * LD];
    __shared__ u64 bufB[W_ * LD];
    __shared__ u64 awT[W_ * LD];
    __shared__ u64 bT[W_ * LD];
    __shared__ u64 Msh[W_];
    __shared__ float scoresL[N_];
    __shared__ float redF[4];

    const int k   = blockIdx.x;
    const int b   = blockIdx.y;
    const int tid = threadIdx.x;

    if (tid < W_)  Msh[tid]    = Mp[b * W_ + tid];
    if (tid < N_)  scoresL[tid] = scores[b * N_ + tid];

    // load tags (coalesced) -> transposed LDS
    for (int x = tid; x < W_ * N_; x += 256) {
        int r = x >> 3, w = x & 7;
        tagsT[w * LD + r] = tags[(long long)b * N_ * W_ + x];
    }
    __syncthreads();

    // init suffix-scan source: rows [0, k)
    for (int x = tid; x < W_ * N_; x += 256) {
        int r = x >> 3, w = x & 7;
        bufA[w * LD + r] = (r < k) ? tagsT[w * LD + r] : 0ull;
    }
    __syncthreads();

    // 8-step Hillis-Steele suffix OR-scan (bounded at row k-1)
    u64* src = bufA;
    u64* dst = bufB;
    for (int d = 1; d < N_; d <<= 1) {
        for (int x = tid; x < W_ * N_; x += 256) {
            int r = x >> 3, w = x & 7;
            u64 v = src[w * LD + r];
            if (r + d < k) v |= src[w * LD + r + d];
            dst[w * LD + r] = v;
        }
        __syncthreads();
        u64* t = src; src = dst; dst = t;
    }
    // src[w*LD+r] = OR of tags[r..k-1]

    // build awT (i-rows) and bT (j-rows)
    for (int x = tid; x < W_ * N_; x += 256) {
        int i = x >> 3, w = x & 7;
        u64 pre;
        if (i == 1) pre = 0ull;
        else {
            int sr = (i == 0) ? (N_ - 2) : (i - 2);
            pre = P[((long long)b * N_ + sr) * W_ + w];
        }
        u64 sv = (i + 1 < k) ? src[w * LD + i + 1] : 0ull;   // k >= i+2
        awT[w * LD + i] = Msh[w] & ~pre & ~sv;
        bT[w * LD + i]  = Msh[w] & ~tagsT[w * LD + i];
    }
    __syncthreads();

    // pair sweep: p = tid + 256*c over i in [0,k], j in [k+1, N)
    const int m = N_ - 1 - k;         // number of j values
    float accLam = 0.0f, accC = 0.0f;
    if (m > 0) {
        const int npairs = (k + 1) * m;
        if (tid < npairs) {
            int cnt = (npairs - tid + 255) >> 8;
            int i   = tid / m;
            int jj  = tid - i * m;
            const int di = 256 / m;
            const int rj = 256 - di * m;
            for (int c = 0; c < cnt; ++c) {
                const int j = k + 1 + jj;
                int cc = 0;
#pragma unroll
                for (int w = 0; w < W_; ++w)
                    cc += __popcll(awT[w * LD + i] & bT[w * LD + j]);
                float lam = 1.0f / (1.0f + __expf(scoresL[i] - scoresL[j]));
                accLam += lam;
                accC   += lam * (float)cc;
                i += di; jj += rj;
                if (jj >= m) { jj -= m; ++i; }
            }
        }
    }

    const float cUk = cU[b * N_ + k];
    float val = cUk * accLam - accC;
    for (int off = 32; off >= 1; off >>= 1) val += __shfl_down(val, off, 64);
    if ((tid & 63) == 0) redF[tid >> 6] = val;
    __syncthreads();
    if (tid == 0) {
        float s = redF[0] + redF[1] + redF[2] + redF[3];
        float invlog = 1.0f / log2f((float)(k + 2));
        partials[b * N_ + k] = (double)(s * invlog) / (double)Mc[b];
    }
}

// ---------------------------------------------------------------------------
// Kernel 4: reduce partials -> scalar. 1 block, 256 threads.
// ---------------------------------------------------------------------------
__global__ __launch_bounds__(256) void finalize(const double* __restrict__ partials,
                                                float* __restrict__ out) {
    __shared__ double redD[4];
    const int tid = threadIdx.x;
    double s = 0.0;
    for (int x = tid; x < B_ * N_; x += 256) s += partials[x];
    for (int off = 32; off >= 1; off >>= 1) s += __shfl_down(s, off, 64);
    if ((tid & 63) == 0) redD[tid >> 6] = s;
    __syncthreads();
    if (tid == 0) {
        double t = redD[0] + redD[1] + redD[2] + redD[3];
        out[0] = (float)(t / ((double)(N_ + 1) * (double)B_));
    }
}

// ---------------------------------------------------------------------------
extern "C" void kernel_launch(void* const* d_in, const int* in_sizes, int n_in,
                              void* d_out, int out_size, void* d_ws, size_t ws_size,
                              hipStream_t stream) {
    const float* y_scores = (const float*)d_in[0];   // B*N f32
    const float* Mf       = (const float*)d_in[1];   // B*T f32
    const float* emb      = (const float*)d_in[2];   // NUM_API*T f32
    const int*   preds    = (const int*)d_in[3];     // B*N i32
    float* out = (float*)d_out;

    // workspace layout (all 8-byte aligned)
    u64* tags = (u64*)d_ws;                               // B*N*W
    u64* P    = tags + (size_t)B_ * N_ * W_;              // B*N*W
    u64* Mp   = P + (size_t)B_ * N_ * W_;                 // B*W
    double* partials = (double*)(Mp + B_ * W_);           // B*N
    float* cU = (float*)(partials + B_ * N_);             // B*N
    float* Mc = cU + B_ * N_;                             // B

    pack_tags<<<B_ * N_, 64, 0, stream>>>(emb, preds, tags);
    pack_scan<<<B_, 256, 0, stream>>>(Mf, tags, Mp, P, cU, Mc);
    dim3 grid(N_, B_);
    lambda_main<<<grid, 256, 0, stream>>>(tags, Mp, P, cU, Mc, y_scores, partials);
    finalize<<<1, 256, 0, stream>>>(partials, out);
}